// Round 6
// baseline (227.247 us; speedup 1.0000x reference)
//
#include <hip/hip_runtime.h>

#define N_NODES 50000
#define N_EDGES 800000
#define CAP 48        // max realized degree ~38 (Binomial(800k,1/50k)); guarded anyway

// --- counting-sort binning parameters ---
#define TILE   2048                       // edges per tile
#define NT     391                        // ceil(800000/2048)
#define NT_PAD 392
#define NB     256                        // coarse bins
#define BIN_NODES 196                     // ceil(50000/256); 49999/196 = 255 ok

typedef __bf16 bf16_t;
typedef bf16_t bf16x8 __attribute__((ext_vector_type(8)));
typedef float f32x16 __attribute__((ext_vector_type(16)));

union Frag { float4 f4; bf16x8 h; };
union Pack8 { ushort u[8]; float4 f4; };

__device__ __forceinline__ ushort f2bf(float f) {   // RNE, inputs never NaN/Inf
    unsigned u = __float_as_uint(f);
    return (ushort)((u + 0x7fffu + ((u >> 16) & 1u)) >> 16);
}
__device__ __forceinline__ float bf2f(unsigned bits) {
    return __uint_as_float(bits << 16);
}

// int64-vs-int32 detection, inline per block: if int64, odd 32-bit words
// (high halves of node ids < 2^31) are all 0. For int32 input, the odd words
// are actual node ids (random in [0,50k)); P(64 sampled all zero) ~ 0.
__device__ __forceinline__ int detect_i64(const int* __restrict__ idx) {
    int lane = threadIdx.x & 63;
    int v = idx[2 * lane + 1];
    unsigned long long b = __ballot(v == 0);
    return (b == 0xFFFFFFFFFFFFFFFFull) ? 1 : 0;
}

__device__ __forceinline__ void load_edge(const int* __restrict__ idx, int f, int e,
                                          int& src, int& dst) {
    if (f) { src = idx[2 * e]; dst = idx[2 * N_EDGES + 2 * e]; }
    else   { src = idx[e];     dst = idx[N_EDGES + e]; }
}
__device__ __forceinline__ int load_dst(const int* __restrict__ idx, int f, int e) {
    return f ? idx[2 * N_EDGES + 2 * e] : idx[N_EDGES + e];
}

// ---------------------------------------------------------------------------
// Fused prep + tile-histogram.
// Blocks [0, XBLK): x f32 -> bf16 pairs; pack B fragments (both layers).
// Blocks [XBLK, XBLK+NT): per-tile coarse histogram of dst/196 via LDS atomics.
#define XBLK ((N_NODES * 64 + 255) / 256)   // 12500
__global__ __launch_bounds__(256) void prep_hist_kernel(
        const float2* __restrict__ X, uint* __restrict__ Xb,
        const float* __restrict__ W1l, const float* __restrict__ W1r,
        const float* __restrict__ W2l, const float* __restrict__ W2r,
        ushort* __restrict__ Bp,
        const int* __restrict__ idx, uint* __restrict__ hist) {
    if (blockIdx.x < XBLK) {
        int i = blockIdx.x * 256 + threadIdx.x;
        if (i < N_NODES * 64) {
            float2 v = X[i];
            Xb[i] = ((uint)f2bf(v.y) << 16) | (uint)f2bf(v.x);
        }
        if (i < 8192) {
            int layer = i >> 12;
            int rec   = i & 4095;
            int t = rec >> 10;
            int s = (rec >> 6) & 15;
            int l = rec & 63;
            const float* Wl = layer ? W2l : W1l;
            const float* Wr = layer ? W2r : W1r;
            int n = t * 32 + (l & 31);
            int kb = s * 16 + (l >> 5) * 8;
            Pack8 o;
#pragma unroll
            for (int j = 0; j < 8; ++j) {
                int k = kb + j;
                float v = (k < 128) ? Wl[k * 128 + n] : Wr[(k - 128) * 128 + n];
                o.u[j] = f2bf(v);
            }
            *(float4*)(Bp + (size_t)i * 8) = o.f4;
        }
        return;
    }
    // --- histogram part ---
    __shared__ uint h[NB];
    const int t   = blockIdx.x - XBLK;
    const int tid = threadIdx.x;
    h[tid] = 0;
    int f = detect_i64(idx);
    __syncthreads();
    const int e0 = t * TILE;
    const int e1 = min(e0 + TILE, N_EDGES);
    for (int e = e0 + tid; e < e1; e += 256) {
        int dst = load_dst(idx, f, e);
        atomicAdd(&h[(uint)dst / BIN_NODES], 1u);       // LDS atomic
    }
    __syncthreads();
    hist[(size_t)tid * NT_PAD + t] = h[tid];            // hist[bin][tile]
}

// ---------------------------------------------------------------------------
// Per-bin exclusive prefix over tiles. Grid NB blocks x 64 threads (1 wave).
__global__ __launch_bounds__(64) void scan_kernel(
        const uint* __restrict__ hist, uint* __restrict__ base,
        uint* __restrict__ total) {
    const int b = blockIdx.x;
    const int lane = threadIdx.x;
    uint run = 0;
    for (int c = 0; c < NT; c += 64) {
        int t = c + lane;
        uint v = (t < NT) ? hist[(size_t)b * NT_PAD + t] : 0u;
        uint x = v;
#pragma unroll
        for (int d = 1; d < 64; d <<= 1) {
            uint y = __shfl_up(x, d);
            if (lane >= d) x += y;
        }
        if (t < NT) base[(size_t)b * NT_PAD + t] = run + (x - v);
        run += __shfl(x, 63);
    }
    if (lane == 0) total[b] = run;
}

// ---------------------------------------------------------------------------
// Scatter edges into coarse-bin segments. slot = binStart[b] + base[b][t] + r,
// r = LDS returning atomic (rank within (tile,bin); order irrelevant for mean).
// Packed entry: (dstLocal << 16) | src  (src < 65536, dstLocal < 196).
__global__ __launch_bounds__(256) void scatter_kernel(
        const int* __restrict__ idx, const uint* __restrict__ base,
        const uint* __restrict__ total, uint* __restrict__ eseg) {
    __shared__ uint s[NB];
    __shared__ uint binoff[NB];
    __shared__ uint lh[NB];
    const int t = blockIdx.x, tid = threadIdx.x;
    int f = detect_i64(idx);
    // block-scan of total[256] -> binStart (inclusive Hillis-Steele)
    uint tot = total[tid];
    s[tid] = tot;
    __syncthreads();
#pragma unroll
    for (int d = 1; d < NB; d <<= 1) {
        uint v = (tid >= d) ? s[tid - d] : 0u;
        __syncthreads();
        s[tid] += v;
        __syncthreads();
    }
    binoff[tid] = (s[tid] - tot) + base[(size_t)tid * NT_PAD + t];
    lh[tid] = 0;
    __syncthreads();
    const int e0 = t * TILE;
    const int e1 = min(e0 + TILE, N_EDGES);
    for (int e = e0 + tid; e < e1; e += 256) {
        int src, dst;
        load_edge(idx, f, e, src, dst);
        uint b  = (uint)dst / BIN_NODES;
        uint dl = (uint)dst - b * BIN_NODES;
        uint r  = atomicAdd(&lh[b], 1u);                // LDS returning atomic
        eseg[binoff[b] + r] = (uint)src | (dl << 16);
    }
}

// ---------------------------------------------------------------------------
// Build per-node lists from a bin's contiguous segment. Grid NB blocks.
// Writes deg (no global atomics anywhere) + full-CAP esrc rows (coalesced).
__global__ __launch_bounds__(256) void build_kernel(
        const uint* __restrict__ eseg, const uint* __restrict__ total,
        int* __restrict__ deg, ushort* __restrict__ esrc) {
    __shared__ uint s[NB];
    __shared__ uint cnt[BIN_NODES];
    __shared__ __align__(16) ushort lists[BIN_NODES * CAP];   // 18816 B
    const int b = blockIdx.x, tid = threadIdx.x;
    uint tot = total[tid];
    s[tid] = tot;
    __syncthreads();
#pragma unroll
    for (int d = 1; d < NB; d <<= 1) {
        uint v = (tid >= d) ? s[tid - d] : 0u;
        __syncthreads();
        s[tid] += v;
        __syncthreads();
    }
    const uint start = (b == 0) ? 0u : s[b - 1];
    const uint cntb  = s[b] - start;
    for (int i = tid; i < BIN_NODES; i += 256) cnt[i] = 0;
    __syncthreads();
    for (uint i = tid; i < cntb; i += 256) {
        uint p  = eseg[start + i];
        uint dl = p >> 16;
        uint r  = atomicAdd(&cnt[dl], 1u);              // LDS returning atomic
        if (r < CAP) lists[dl * CAP + r] = (ushort)(p & 0xffffu);
    }
    __syncthreads();
    const int node0 = b * BIN_NODES;
    const int valid = min(BIN_NODES, N_NODES - node0);  // b=255 -> 20 valid
    for (int i = tid; i < valid; i += 256)
        deg[node0 + i] = (int)cnt[i];
    // full-CAP rows, uint4-vectorized (CAP*2 = 96 B = 6 x uint4 per node)
    const int nvec = valid * 6;
    uint4* dst4 = (uint4*)(esrc + (size_t)node0 * CAP);
    const uint4* src4 = (const uint4*)lists;
    for (int i = tid; i < nvec; i += 256) dst4[i] = src4[i];
}

// ---------------------------------------------------------------------------
// Gather + mean, wide-load version (round-4 proven config). One node per
// WAVE. Quarter-wave q owns edges {q, q+4, ...}; a row is read as 16 lanes x
// uint4 = 256 B (row stride = 16 uint4). Unroll-2 keeps two 1 KB loads in
// flight per wave. bf16 unpack exact via shift/mask. Cross-quarter reduce
// via shfl_xor(16/32); quarter 0 stores the 256 B mean row.
#define ACC8(v)                                                                 \
    c[0] += bf2f((v).x & 0xffffu); c[1] += __uint_as_float((v).x & 0xffff0000u);\
    c[2] += bf2f((v).y & 0xffffu); c[3] += __uint_as_float((v).y & 0xffff0000u);\
    c[4] += bf2f((v).z & 0xffffu); c[5] += __uint_as_float((v).z & 0xffff0000u);\
    c[6] += bf2f((v).w & 0xffffu); c[7] += __uint_as_float((v).w & 0xffff0000u);

__global__ __launch_bounds__(256) void gather_mean_kernel(
        const uint4* __restrict__ X4, const int* __restrict__ deg,
        const ushort* __restrict__ esrc, uint4* __restrict__ mean4) {
    const int wave = threadIdx.x >> 6;
    const int lane = threadIdx.x & 63;
    const int q  = lane >> 4;           // quarter-wave 0..3
    const int ql = lane & 15;
    const int node = blockIdx.x * 4 + wave;
    if (node >= N_NODES) return;
    int dg = deg[node];
    if (dg > CAP) dg = CAP;
    const ushort* es = esrc + node * CAP;

    float c[8] = {0, 0, 0, 0, 0, 0, 0, 0};
    int p = q;
    for (; p + 4 < dg; p += 8) {
        uint s0 = es[p];
        uint s1 = es[p + 4];
        uint4 v0 = X4[(size_t)s0 * 16 + ql];
        uint4 v1 = X4[(size_t)s1 * 16 + ql];
        ACC8(v0); ACC8(v1);
    }
    if (p < dg) {
        uint s0 = es[p];
        uint4 v0 = X4[(size_t)s0 * 16 + ql];
        ACC8(v0);
    }
    // reduce across the 4 quarter-waves (lanes l, l^16, l^32, l^48)
#pragma unroll
    for (int j = 0; j < 8; ++j) {
        c[j] += __shfl_xor(c[j], 16);
        c[j] += __shfl_xor(c[j], 32);
    }
    if (q == 0) {
        const float inv = 1.0f / (float)max(dg, 1);
        uint4 m;
        m.x = ((uint)f2bf(c[1] * inv) << 16) | (uint)f2bf(c[0] * inv);
        m.y = ((uint)f2bf(c[3] * inv) << 16) | (uint)f2bf(c[2] * inv);
        m.z = ((uint)f2bf(c[5] * inv) << 16) | (uint)f2bf(c[4] * inv);
        m.w = ((uint)f2bf(c[7] * inv) << 16) | (uint)f2bf(c[6] * inv);
        mean4[(size_t)node * 16 + ql] = m;
    }
}

// ---------------------------------------------------------------------------
// MFMA GEMM, BM=64, 512 threads / 8 waves: C = [mean | self](M x 256 bf16)
// @ Bpack(256 x 128 bf16) + bias, fused row-L2-norm + ReLU. Wave w: row-half
// rh = w&1 (rows rh*32), col-tile ct = w>>1 (cols ct*32); 16 MFMA + 32 loads
// per wave (vs 32+48 in the 4-wave version). Same grid (782) and same
// per-block B traffic as BM=64/4-wave, but 24 waves/CU instead of 12 -> 2x
// latency hiding for the dependent global-load chain. No LDS staging.
// In-place Aself==Y is safe: Aself reads are block-local rows and
// __syncthreads() after the K-loop orders all A reads before any store.
// Pad rows (>= N_NODES) read trailing buffers (harmless; stores guarded).
template<bool OUT_F32>
__global__ __launch_bounds__(512) void gemm_mfma_kernel(
        const ushort* __restrict__ Amean, const ushort* Aself,
        const ushort* __restrict__ Bpack, const float* __restrict__ bias,
        void* Yout) {
    __shared__ float rs[4][64];
    const int tid = threadIdx.x;
    const int w = tid >> 6, l = tid & 63;
    const int lr = l & 31, lh = l >> 5;
    const int rh = w & 1;                   // row half 0..1
    const int ct = w >> 1;                  // col tile 0..3
    const int mrow0 = blockIdx.x * 64 + rh * 32;

    f32x16 acc;
#pragma unroll
    for (int i = 0; i < 16; ++i) acc[i] = 0.0f;

#pragma unroll
    for (int s = 0; s < 16; ++s) {
        const ushort* Ab = (s < 8) ? Amean : Aself;
        Frag a, b;
        a.f4 = *(const float4*)(Ab + (size_t)(mrow0 + lr) * 128 + (s & 7) * 16 + lh * 8);
        b.f4 = *(const float4*)(Bpack + (size_t)((ct * 16 + s) * 64 + l) * 8);
        acc = __builtin_amdgcn_mfma_f32_32x32x16_bf16(a.h, b.h, acc, 0, 0, 0);
    }

    const float bia = bias[ct * 32 + lr];
    float sq[16];
#pragma unroll
    for (int r = 0; r < 16; ++r) {
        float v = acc[r] + bia;
        acc[r] = v;
        float s_ = v * v;                      // this wave's 32 cols
        s_ += __shfl_xor(s_, 1);
        s_ += __shfl_xor(s_, 2);
        s_ += __shfl_xor(s_, 4);
        s_ += __shfl_xor(s_, 8);
        s_ += __shfl_xor(s_, 16);              // reduce over lr (row-preserving)
        sq[r] = s_;
    }
    if (lr == 0) {
#pragma unroll
        for (int r = 0; r < 16; ++r) {
            int rowl = rh * 32 + (r & 3) + 8 * (r >> 2) + 4 * lh;
            rs[ct][rowl] = sq[r];              // unique (ct,rowl) writer
        }
    }
    __syncthreads();                            // also orders A-reads vs stores
#pragma unroll
    for (int r = 0; r < 16; ++r) {
        int rowl = rh * 32 + (r & 3) + 8 * (r >> 2) + 4 * lh;
        int grow = blockIdx.x * 64 + rowl;
        float tot = rs[0][rowl] + rs[1][rowl] + rs[2][rowl] + rs[3][rowl];
        float sc = 1.0f / fmaxf(sqrtf(tot), 1e-12f);
        if (grow < N_NODES) {
            float o = fmaxf(acc[r] * sc, 0.0f);
            if (OUT_F32) {
                float* Y = (float*)Yout;
                Y[(size_t)grow * 128 + ct * 32 + lr] = o;
            } else {
                ushort* Y = (ushort*)Yout;
                Y[(size_t)grow * 128 + ct * 32 + lr] = f2bf(o);
            }
        }
    }
}

extern "C" void kernel_launch(void* const* d_in, const int* in_sizes, int n_in,
                              void* d_out, int out_size, void* d_ws, size_t ws_size,
                              hipStream_t stream) {
    const float* x    = (const float*)d_in[0];
    const int*   idx  = (const int*)d_in[1];
    const float* W1l  = (const float*)d_in[2];
    const float* b1l  = (const float*)d_in[3];
    const float* W1r  = (const float*)d_in[4];
    const float* W2l  = (const float*)d_in[5];
    const float* b2l  = (const float*)d_in[6];
    const float* W2r  = (const float*)d_in[7];
    float* out = (float*)d_out;

    // ws layout (4B-word offsets).
    // Aliasing by lifetime:
    //   hist/base live inside esrc region  (dead before build writes esrc)
    //   eseg/total live inside meanb region (dead before gather writes meanb)
    int*    deg   = (int*)d_ws;                         // [50000]
    ushort* esrc  = (ushort*)((int*)d_ws + 50016);      // [50000*48] = 1.2M words
    uint*   hist  = (uint*)((int*)d_ws + 50016);        // [256*392]  (alias esrc)
    uint*   base  = hist + NB * NT_PAD;                 // [256*392]  (alias esrc)
    uint*   meanb = (uint*)((int*)d_ws + 1250016);      // [50000*64]
    uint*   eseg  = meanb;                              // [800000]   (alias meanb)
    uint*   total = meanb + 800000;                     // [256]      (alias meanb)
    uint*   xh    = (uint*)((int*)d_ws + 4450016);      // [50000*64]
    ushort* Bp    = (ushort*)((int*)d_ws + 7650016);    // [2*4096*8] (also absorbs
                                                        //  GEMM pad-row reads of xh)

    // prep (x->bf16, B-pack) + per-tile coarse histogram, one kernel
    prep_hist_kernel<<<XBLK + NT, 256, 0, stream>>>(
        (const float2*)x, xh, W1l, W1r, W2l, W2r, Bp, idx, hist);
    scan_kernel<<<NB, 64, 0, stream>>>(hist, base, total);
    scatter_kernel<<<NT, 256, 0, stream>>>(idx, base, total, eseg);
    build_kernel<<<NB, 256, 0, stream>>>(eseg, total, deg, esrc);

    const int gb = (N_NODES + 3) / 4;               // 12500 (4 nodes/block, 1/wave)
    const int mb = (N_NODES + 63) / 64;             // 782 (BM=64, 512 threads)

    // layer 1: gather(xh)->meanb; GEMM writes h1 (bf16) in-place over xh
    gather_mean_kernel<<<gb, 256, 0, stream>>>(
        (const uint4*)xh, deg, esrc, (uint4*)meanb);
    gemm_mfma_kernel<false><<<mb, 512, 0, stream>>>(
        (const ushort*)meanb, (const ushort*)xh, Bp, b1l, (void*)xh);
    // layer 2: gather(h1)->meanb; GEMM writes f32 d_out
    gather_mean_kernel<<<gb, 256, 0, stream>>>(
        (const uint4*)xh, deg, esrc, (uint4*)meanb);
    gemm_mfma_kernel<true><<<mb, 512, 0, stream>>>(
        (const ushort*)meanb, (const ushort*)xh, Bp + 4096 * 8, b2l, (void*)out);
}

// Round 7
// 213.985 us; speedup vs baseline: 1.0620x; 1.0620x over previous
//
#include <hip/hip_runtime.h>

#define N_NODES 50000
#define N_EDGES 800000
#define CAP 48        // max realized degree ~38 (Binomial(800k,1/50k)); guarded anyway

// --- counting-sort binning parameters ---
#define TILE   2048                       // edges per tile
#define NT     391                        // ceil(800000/2048)
#define NT_PAD 392
#define NB     256                        // coarse bins
#define BIN_NODES 196                     // ceil(50000/256); 49999/196 = 255 ok

typedef __bf16 bf16_t;
typedef bf16_t bf16x8 __attribute__((ext_vector_type(8)));
typedef float f32x16 __attribute__((ext_vector_type(16)));

union Frag { float4 f4; bf16x8 h; };
union Pack8 { ushort u[8]; float4 f4; };

__device__ __forceinline__ ushort f2bf(float f) {   // RNE, inputs never NaN/Inf
    unsigned u = __float_as_uint(f);
    return (ushort)((u + 0x7fffu + ((u >> 16) & 1u)) >> 16);
}
__device__ __forceinline__ float bf2f(unsigned bits) {
    return __uint_as_float(bits << 16);
}

// int64-vs-int32 detection, inline per block: if int64, odd 32-bit words
// (high halves of node ids < 2^31) are all 0. For int32 input, the odd words
// are actual node ids (random in [0,50k)); P(64 sampled all zero) ~ 0.
__device__ __forceinline__ int detect_i64(const int* __restrict__ idx) {
    int lane = threadIdx.x & 63;
    int v = idx[2 * lane + 1];
    unsigned long long b = __ballot(v == 0);
    return (b == 0xFFFFFFFFFFFFFFFFull) ? 1 : 0;
}

__device__ __forceinline__ void load_edge(const int* __restrict__ idx, int f, int e,
                                          int& src, int& dst) {
    if (f) { src = idx[2 * e]; dst = idx[2 * N_EDGES + 2 * e]; }
    else   { src = idx[e];     dst = idx[N_EDGES + e]; }
}
__device__ __forceinline__ int load_dst(const int* __restrict__ idx, int f, int e) {
    return f ? idx[2 * N_EDGES + 2 * e] : idx[N_EDGES + e];
}

// ---------------------------------------------------------------------------
// Fused prep + tile-histogram.
// Blocks [0, XBLK): x f32 -> bf16 pairs; pack B fragments (both layers).
// Blocks [XBLK, XBLK+NT): per-tile coarse histogram of dst/196 via LDS atomics.
#define XBLK ((N_NODES * 64 + 255) / 256)   // 12500
__global__ __launch_bounds__(256) void prep_hist_kernel(
        const float2* __restrict__ X, uint* __restrict__ Xb,
        const float* __restrict__ W1l, const float* __restrict__ W1r,
        const float* __restrict__ W2l, const float* __restrict__ W2r,
        ushort* __restrict__ Bp,
        const int* __restrict__ idx, uint* __restrict__ hist) {
    if (blockIdx.x < XBLK) {
        int i = blockIdx.x * 256 + threadIdx.x;
        if (i < N_NODES * 64) {
            float2 v = X[i];
            Xb[i] = ((uint)f2bf(v.y) << 16) | (uint)f2bf(v.x);
        }
        if (i < 8192) {
            int layer = i >> 12;
            int rec   = i & 4095;
            int t = rec >> 10;
            int s = (rec >> 6) & 15;
            int l = rec & 63;
            const float* Wl = layer ? W2l : W1l;
            const float* Wr = layer ? W2r : W1r;
            int n = t * 32 + (l & 31);
            int kb = s * 16 + (l >> 5) * 8;
            Pack8 o;
#pragma unroll
            for (int j = 0; j < 8; ++j) {
                int k = kb + j;
                float v = (k < 128) ? Wl[k * 128 + n] : Wr[(k - 128) * 128 + n];
                o.u[j] = f2bf(v);
            }
            *(float4*)(Bp + (size_t)i * 8) = o.f4;
        }
        return;
    }
    // --- histogram part ---
    __shared__ uint h[NB];
    const int t   = blockIdx.x - XBLK;
    const int tid = threadIdx.x;
    h[tid] = 0;
    int f = detect_i64(idx);
    __syncthreads();
    const int e0 = t * TILE;
    const int e1 = min(e0 + TILE, N_EDGES);
    for (int e = e0 + tid; e < e1; e += 256) {
        int dst = load_dst(idx, f, e);
        atomicAdd(&h[(uint)dst / BIN_NODES], 1u);       // LDS atomic
    }
    __syncthreads();
    hist[(size_t)tid * NT_PAD + t] = h[tid];            // hist[bin][tile]
}

// ---------------------------------------------------------------------------
// Per-bin exclusive prefix over tiles. Grid NB blocks x 64 threads (1 wave).
__global__ __launch_bounds__(64) void scan_kernel(
        const uint* __restrict__ hist, uint* __restrict__ base,
        uint* __restrict__ total) {
    const int b = blockIdx.x;
    const int lane = threadIdx.x;
    uint run = 0;
    for (int c = 0; c < NT; c += 64) {
        int t = c + lane;
        uint v = (t < NT) ? hist[(size_t)b * NT_PAD + t] : 0u;
        uint x = v;
#pragma unroll
        for (int d = 1; d < 64; d <<= 1) {
            uint y = __shfl_up(x, d);
            if (lane >= d) x += y;
        }
        if (t < NT) base[(size_t)b * NT_PAD + t] = run + (x - v);
        run += __shfl(x, 63);
    }
    if (lane == 0) total[b] = run;
}

// ---------------------------------------------------------------------------
// Scatter edges into coarse-bin segments. slot = binStart[b] + base[b][t] + r,
// r = LDS returning atomic (rank within (tile,bin); order irrelevant for mean).
// Packed entry: (dstLocal << 16) | src  (src < 65536, dstLocal < 196).
__global__ __launch_bounds__(256) void scatter_kernel(
        const int* __restrict__ idx, const uint* __restrict__ base,
        const uint* __restrict__ total, uint* __restrict__ eseg) {
    __shared__ uint s[NB];
    __shared__ uint binoff[NB];
    __shared__ uint lh[NB];
    const int t = blockIdx.x, tid = threadIdx.x;
    int f = detect_i64(idx);
    // block-scan of total[256] -> binStart (inclusive Hillis-Steele)
    uint tot = total[tid];
    s[tid] = tot;
    __syncthreads();
#pragma unroll
    for (int d = 1; d < NB; d <<= 1) {
        uint v = (tid >= d) ? s[tid - d] : 0u;
        __syncthreads();
        s[tid] += v;
        __syncthreads();
    }
    binoff[tid] = (s[tid] - tot) + base[(size_t)tid * NT_PAD + t];
    lh[tid] = 0;
    __syncthreads();
    const int e0 = t * TILE;
    const int e1 = min(e0 + TILE, N_EDGES);
    for (int e = e0 + tid; e < e1; e += 256) {
        int src, dst;
        load_edge(idx, f, e, src, dst);
        uint b  = (uint)dst / BIN_NODES;
        uint dl = (uint)dst - b * BIN_NODES;
        uint r  = atomicAdd(&lh[b], 1u);                // LDS returning atomic
        eseg[binoff[b] + r] = (uint)src | (dl << 16);
    }
}

// ---------------------------------------------------------------------------
// Build per-node lists from a bin's contiguous segment. Grid NB blocks.
// Writes deg (no global atomics anywhere) + full-CAP esrc rows (coalesced).
__global__ __launch_bounds__(256) void build_kernel(
        const uint* __restrict__ eseg, const uint* __restrict__ total,
        int* __restrict__ deg, ushort* __restrict__ esrc) {
    __shared__ uint s[NB];
    __shared__ uint cnt[BIN_NODES];
    __shared__ __align__(16) ushort lists[BIN_NODES * CAP];   // 18816 B
    const int b = blockIdx.x, tid = threadIdx.x;
    uint tot = total[tid];
    s[tid] = tot;
    __syncthreads();
#pragma unroll
    for (int d = 1; d < NB; d <<= 1) {
        uint v = (tid >= d) ? s[tid - d] : 0u;
        __syncthreads();
        s[tid] += v;
        __syncthreads();
    }
    const uint start = (b == 0) ? 0u : s[b - 1];
    const uint cntb  = s[b] - start;
    for (int i = tid; i < BIN_NODES; i += 256) cnt[i] = 0;
    __syncthreads();
    for (uint i = tid; i < cntb; i += 256) {
        uint p  = eseg[start + i];
        uint dl = p >> 16;
        uint r  = atomicAdd(&cnt[dl], 1u);              // LDS returning atomic
        if (r < CAP) lists[dl * CAP + r] = (ushort)(p & 0xffffu);
    }
    __syncthreads();
    const int node0 = b * BIN_NODES;
    const int valid = min(BIN_NODES, N_NODES - node0);  // b=255 -> 20 valid
    for (int i = tid; i < valid; i += 256)
        deg[node0 + i] = (int)cnt[i];
    // full-CAP rows, uint4-vectorized (CAP*2 = 96 B = 6 x uint4 per node)
    const int nvec = valid * 6;
    uint4* dst4 = (uint4*)(esrc + (size_t)node0 * CAP);
    const uint4* src4 = (const uint4*)lists;
    for (int i = tid; i < nvec; i += 256) dst4[i] = src4[i];
}

// ---------------------------------------------------------------------------
// Gather + mean, wide-load version (round-4 proven config). One node per
// WAVE. Quarter-wave q owns edges {q, q+4, ...}; a row is read as 16 lanes x
// uint4 = 256 B (row stride = 16 uint4). Unroll-2 keeps two 1 KB loads in
// flight per wave. bf16 unpack exact via shift/mask. Cross-quarter reduce
// via shfl_xor(16/32); quarter 0 stores the 256 B mean row.
#define ACC8(v)                                                                 \
    c[0] += bf2f((v).x & 0xffffu); c[1] += __uint_as_float((v).x & 0xffff0000u);\
    c[2] += bf2f((v).y & 0xffffu); c[3] += __uint_as_float((v).y & 0xffff0000u);\
    c[4] += bf2f((v).z & 0xffffu); c[5] += __uint_as_float((v).z & 0xffff0000u);\
    c[6] += bf2f((v).w & 0xffffu); c[7] += __uint_as_float((v).w & 0xffff0000u);

__global__ __launch_bounds__(256) void gather_mean_kernel(
        const uint4* __restrict__ X4, const int* __restrict__ deg,
        const ushort* __restrict__ esrc, uint4* __restrict__ mean4) {
    const int wave = threadIdx.x >> 6;
    const int lane = threadIdx.x & 63;
    const int q  = lane >> 4;           // quarter-wave 0..3
    const int ql = lane & 15;
    const int node = blockIdx.x * 4 + wave;
    if (node >= N_NODES) return;
    int dg = deg[node];
    if (dg > CAP) dg = CAP;
    const ushort* es = esrc + node * CAP;

    float c[8] = {0, 0, 0, 0, 0, 0, 0, 0};
    int p = q;
    for (; p + 4 < dg; p += 8) {
        uint s0 = es[p];
        uint s1 = es[p + 4];
        uint4 v0 = X4[(size_t)s0 * 16 + ql];
        uint4 v1 = X4[(size_t)s1 * 16 + ql];
        ACC8(v0); ACC8(v1);
    }
    if (p < dg) {
        uint s0 = es[p];
        uint4 v0 = X4[(size_t)s0 * 16 + ql];
        ACC8(v0);
    }
    // reduce across the 4 quarter-waves (lanes l, l^16, l^32, l^48)
#pragma unroll
    for (int j = 0; j < 8; ++j) {
        c[j] += __shfl_xor(c[j], 16);
        c[j] += __shfl_xor(c[j], 32);
    }
    if (q == 0) {
        const float inv = 1.0f / (float)max(dg, 1);
        uint4 m;
        m.x = ((uint)f2bf(c[1] * inv) << 16) | (uint)f2bf(c[0] * inv);
        m.y = ((uint)f2bf(c[3] * inv) << 16) | (uint)f2bf(c[2] * inv);
        m.z = ((uint)f2bf(c[5] * inv) << 16) | (uint)f2bf(c[4] * inv);
        m.w = ((uint)f2bf(c[7] * inv) << 16) | (uint)f2bf(c[6] * inv);
        mean4[(size_t)node * 16 + ql] = m;
    }
}

// ---------------------------------------------------------------------------
// MFMA GEMM, BM=64, 4 waves (round-4 shape) + explicit 2-phase fragment
// staging. C = [mean | self](M x 256 bf16) @ Bpack(256 x 128 bf16) + bias,
// fused row-L2-norm + ReLU. Wave w: rows (w&1)*32, col-tiles t0=(w>>1)*2,
// t0+1. Each phase stages 24 fragments (a[8], b0[8], b1[8] -- all indices
// compile-time) BEFORE its 16 MFMAs, so ~24 loads are in flight per wave
// instead of the compiler's minimal-register 1-2 (R4 compiled to 60 VGPR).
// ~150 VGPR keeps 3 waves/SIMD -- grid (782 = 3.05 blocks/CU) stays the
// occupancy limit. In-place Aself==Y safe: __syncthreads() after the K-loop
// orders all A reads before any store. Pad rows (>= N_NODES) read trailing
// buffers (harmless; stores guarded).
template<bool OUT_F32>
__global__ __launch_bounds__(256) void gemm_mfma_kernel(
        const ushort* __restrict__ Amean, const ushort* Aself,
        const ushort* __restrict__ Bpack, const float* __restrict__ bias,
        void* Yout) {
    __shared__ float rs[2][64];
    const int tid = threadIdx.x;
    const int w = tid >> 6, l = tid & 63;
    const int lr = l & 31, lh = l >> 5;
    const int mrow0 = blockIdx.x * 64 + (w & 1) * 32;
    const int t0 = (w >> 1) * 2;

    f32x16 acc0, acc1;
#pragma unroll
    for (int i = 0; i < 16; ++i) { acc0[i] = 0.0f; acc1[i] = 0.0f; }

    const ushort* Abase0 = Amean;
    const ushort* Abase1 = Aself;
#pragma unroll
    for (int ph = 0; ph < 2; ++ph) {
        const ushort* Ab = ph ? Abase1 : Abase0;
        Frag a[8], b0[8], b1[8];
#pragma unroll
        for (int k = 0; k < 8; ++k) {
            const int s = ph * 8 + k;
            a[k].f4  = *(const float4*)(Ab + (size_t)(mrow0 + lr) * 128 + k * 16 + lh * 8);
            b0[k].f4 = *(const float4*)(Bpack + (size_t)(((t0) * 16 + s) * 64 + l) * 8);
            b1[k].f4 = *(const float4*)(Bpack + (size_t)(((t0 + 1) * 16 + s) * 64 + l) * 8);
        }
#pragma unroll
        for (int k = 0; k < 8; ++k) {
            acc0 = __builtin_amdgcn_mfma_f32_32x32x16_bf16(a[k].h, b0[k].h, acc0, 0, 0, 0);
            acc1 = __builtin_amdgcn_mfma_f32_32x32x16_bf16(a[k].h, b1[k].h, acc1, 0, 0, 0);
        }
    }

    const float bia0 = bias[t0 * 32 + lr];
    const float bia1 = bias[t0 * 32 + 32 + lr];
    float sq[16];
#pragma unroll
    for (int r = 0; r < 16; ++r) {
        float v0 = acc0[r] + bia0;
        float v1 = acc1[r] + bia1;
        acc0[r] = v0; acc1[r] = v1;
        float s_ = v0 * v0 + v1 * v1;          // this wave's 64 cols
        s_ += __shfl_xor(s_, 1);
        s_ += __shfl_xor(s_, 2);
        s_ += __shfl_xor(s_, 4);
        s_ += __shfl_xor(s_, 8);
        s_ += __shfl_xor(s_, 16);              // reduce over lr (row-preserving)
        sq[r] = s_;
    }
    if (lr == 0) {
#pragma unroll
        for (int r = 0; r < 16; ++r) {
            int rowl = (w & 1) * 32 + (r & 3) + 8 * (r >> 2) + 4 * lh;
            rs[w >> 1][rowl] = sq[r];          // unique (w>>1,rowl) writer
        }
    }
    __syncthreads();                            // also orders A-reads vs stores
#pragma unroll
    for (int r = 0; r < 16; ++r) {
        int rowl = (w & 1) * 32 + (r & 3) + 8 * (r >> 2) + 4 * lh;
        int grow = blockIdx.x * 64 + rowl;
        float tot = rs[0][rowl] + rs[1][rowl];
        float sc = 1.0f / fmaxf(sqrtf(tot), 1e-12f);
        if (grow < N_NODES) {
            float o0 = fmaxf(acc0[r] * sc, 0.0f);
            float o1 = fmaxf(acc1[r] * sc, 0.0f);
            if (OUT_F32) {
                float* Y = (float*)Yout;
                Y[(size_t)grow * 128 + t0 * 32 + lr]      = o0;
                Y[(size_t)grow * 128 + t0 * 32 + 32 + lr] = o1;
            } else {
                ushort* Y = (ushort*)Yout;
                Y[(size_t)grow * 128 + t0 * 32 + lr]      = f2bf(o0);
                Y[(size_t)grow * 128 + t0 * 32 + 32 + lr] = f2bf(o1);
            }
        }
    }
}

extern "C" void kernel_launch(void* const* d_in, const int* in_sizes, int n_in,
                              void* d_out, int out_size, void* d_ws, size_t ws_size,
                              hipStream_t stream) {
    const float* x    = (const float*)d_in[0];
    const int*   idx  = (const int*)d_in[1];
    const float* W1l  = (const float*)d_in[2];
    const float* b1l  = (const float*)d_in[3];
    const float* W1r  = (const float*)d_in[4];
    const float* W2l  = (const float*)d_in[5];
    const float* b2l  = (const float*)d_in[6];
    const float* W2r  = (const float*)d_in[7];
    float* out = (float*)d_out;

    // ws layout (4B-word offsets).
    // Aliasing by lifetime:
    //   hist/base live inside esrc region  (dead before build writes esrc)
    //   eseg/total live inside meanb region (dead before gather writes meanb)
    int*    deg   = (int*)d_ws;                         // [50000]
    ushort* esrc  = (ushort*)((int*)d_ws + 50016);      // [50000*48] = 1.2M words
    uint*   hist  = (uint*)((int*)d_ws + 50016);        // [256*392]  (alias esrc)
    uint*   base  = hist + NB * NT_PAD;                 // [256*392]  (alias esrc)
    uint*   meanb = (uint*)((int*)d_ws + 1250016);      // [50000*64]
    uint*   eseg  = meanb;                              // [800000]   (alias meanb)
    uint*   total = meanb + 800000;                     // [256]      (alias meanb)
    uint*   xh    = (uint*)((int*)d_ws + 4450016);      // [50000*64]
    ushort* Bp    = (ushort*)((int*)d_ws + 7650016);    // [2*4096*8] (also absorbs
                                                        //  GEMM pad-row reads of xh)

    // prep (x->bf16, B-pack) + per-tile coarse histogram, one kernel
    prep_hist_kernel<<<XBLK + NT, 256, 0, stream>>>(
        (const float2*)x, xh, W1l, W1r, W2l, W2r, Bp, idx, hist);
    scan_kernel<<<NB, 64, 0, stream>>>(hist, base, total);
    scatter_kernel<<<NT, 256, 0, stream>>>(idx, base, total, eseg);
    build_kernel<<<NB, 256, 0, stream>>>(eseg, total, deg, esrc);

    const int gb = (N_NODES + 3) / 4;               // 12500 (4 nodes/block, 1/wave)
    const int mb = (N_NODES + 63) / 64;             // 782 (BM=64, 4 waves)

    // layer 1: gather(xh)->meanb; GEMM writes h1 (bf16) in-place over xh
    gather_mean_kernel<<<gb, 256, 0, stream>>>(
        (const uint4*)xh, deg, esrc, (uint4*)meanb);
    gemm_mfma_kernel<false><<<mb, 256, 0, stream>>>(
        (const ushort*)meanb, (const ushort*)xh, Bp, b1l, (void*)xh);
    // layer 2: gather(h1)->meanb; GEMM writes f32 d_out
    gather_mean_kernel<<<gb, 256, 0, stream>>>(
        (const uint4*)xh, deg, esrc, (uint4*)meanb);
    gemm_mfma_kernel<true><<<mb, 256, 0, stream>>>(
        (const ushort*)meanb, (const ushort*)xh, Bp + 4096 * 8, b2l, (void*)out);
}